// Round 10
// baseline (32533.444 us; speedup 1.0000x reference)
//
#include <hip/hip_runtime.h>

#define H 1024
#define T 4096
#define NLAUNCH 256      // launched blocks; workers are blockIdx%8==0 (32 of them)
#define TPB 1024         // 16 waves per block, 2 adjacent units per wave
#define SOLVE_ITERS 48   // Richardson: rho ~ 0.64 -> 0.64^48 ~ 5e-10
#define FAST_SPINS 16    // bounded intra-XCD poll before slow fallback

typedef float v2f __attribute__((ext_vector_type(2)));
typedef unsigned long long u64;
typedef u64 u64x2 __attribute__((ext_vector_type(2)));

__device__ __forceinline__ float sigmoidf_(float x) { return 1.0f / (1.0f + __expf(-x)); }
__device__ __forceinline__ float tanh_fast_(float x) { return 2.0f * sigmoidf_(2.0f * x) - 1.0f; }

// ---------- epoch-salted checked pairs (R3/R7-proven validation) ----------
__device__ __forceinline__ u64 pack_(float v, unsigned salt) {
    const unsigned lo = __float_as_uint(v);
    return ((u64)(lo ^ salt) << 32) | lo;
}
__device__ __forceinline__ int valid_(u64 v, unsigned salt) {
    return (((unsigned)(v >> 32)) ^ (unsigned)v) == salt;
}
// slow publish: 8B agent-scope atomic store (write-through -> MALL-visible; R7)
__device__ __forceinline__ void pub_(u64* p, u64 pk) {
    __hip_atomic_store(p, pk, __ATOMIC_RELAXED, __HIP_MEMORY_SCOPE_AGENT);
}
// fast poll: L1-bypass only -> served by the XCD-local L2 (sees local plain stores)
__device__ __forceinline__ u64x2 load16_sc0_(const u64* p) {
    u64x2 v;
    asm volatile("global_load_dwordx4 %0, %1, off sc0\n\ts_waitcnt vmcnt(0)"
                 : "=v"(v) : "v"(p) : "memory");
    return v;
}
// slow poll: L1+L2 bypass -> observes remote agent-scope stores at the MALL (R7)
__device__ __forceinline__ u64x2 load16_coh_(const u64* p) {
    u64x2 v;
    asm volatile("global_load_dwordx4 %0, %1, off sc0 sc1\n\ts_waitcnt vmcnt(0)"
                 : "=v"(v) : "v"(p) : "memory");
    return v;
}

// Publish units j, j+1 (j even) for epoch e: 16B plain store to fast region
// (lands in the workers' shared L2 if co-XCD) + two 8B agent stores to the
// slow region (R7 transport, guarantees liveness regardless of placement).
__device__ __forceinline__ void publish2_(u64* fastb, u64* slowb, int e, int j,
                                          float va, float vb) {
    const unsigned salt = ~(unsigned)e;
    u64x2 pk;
    pk.x = pack_(va, salt);
    pk.y = pack_(vb, salt);
    *(volatile u64x2*)(fastb + (size_t)(e & 1) * H + j) = pk;   // local consumers first
    u64* s = slowb + (size_t)(e & 1) * H + j;
    pub_(&s[0], pk.x);
    pub_(&s[1], pk.y);
}

// Consume units j2, j2+1 of epoch e. Bounded fast spins (credits-gated),
// then the R7-proven slow poll (unbounded; live by single-group back-pressure).
// Discriminator: slow validating on the FIRST try while fast failed means the
// fast transport is broken (data was old) -> decrement credits; if slow also
// spun, the producer was merely late -> no penalty. credits==0 -> skip fast
// (pure R7 mode), with a cheap periodic probe for recovery.
__device__ __forceinline__ v2f consume2_(const u64* fastb, const u64* slowb,
                                         int e, int j2, int& credits) {
    const unsigned salt = ~(unsigned)e;
    const size_t off = (size_t)(e & 1) * H + j2;
    if (credits == 0 && (e & 255) == 0) credits = 1;
    if (credits > 0) {
        const u64* pf = fastb + off;
        for (int s = 0; s < FAST_SPINS; ++s) {
            const u64x2 v = load16_sc0_(pf);
            if (valid_(v.x, salt) && valid_(v.y, salt)) {
                credits = 8;
                v2f r;
                r.x = __uint_as_float((unsigned)v.x);
                r.y = __uint_as_float((unsigned)v.y);
                return r;
            }
        }
    }
    const u64* ps = slowb + off;
    int first = (credits > 0) ? 1 : 0;
    for (;;) {
        const u64x2 v = load16_coh_(ps);
        if (valid_(v.x, salt) && valid_(v.y, salt)) {
            credits -= first;
            v2f r;
            r.x = __uint_as_float((unsigned)v.x);
            r.y = __uint_as_float((unsigned)v.y);
            return r;
        }
        first = 0;
    }
}

// Persistent kernel. 256 blocks launched; only blockIdx%8==0 work (32 blocks,
// all on one XCD if dispatch round-robins XCDs by blockIdx%8); the rest exit
// immediately and free their CUs. Single worker group -> R3/R7 back-pressure
// invariant holds for BOTH 2-deep buffers (no lap hazard). Hang-proof: worst
// case degenerates to exactly the R7 protocol.
__global__ __launch_bounds__(TPB) void rnn_kernel(
    const float* __restrict__ u0,
    const float* __restrict__ W_hh,
    const float* __restrict__ b_ih,
    const float* __restrict__ b_hh,
    const float* __restrict__ Amat,
    const float* __restrict__ c,
    float* __restrict__ out,
    u64* __restrict__ fastb,         // ws: 2*H u64
    u64* __restrict__ slowb)         // ws: 2*H u64
{
    if (blockIdx.x & 7) return;      // placement filler
    const int blk = blockIdx.x >> 3; // worker 0..31

    __shared__ float hlds[2][H];
    const int tid  = threadIdx.x;
    const int lane = tid & 63;
    const int wave = tid >> 6;
    const int jA   = blk * 32 + 2 * wave;   // even; wave owns jA, jA+1
    const int jB   = jA + 1;

    // ---- preload GRU weights as float2, paired with h[2*lane + 128k] ----
    v2f wA[3][8], wB[3][8];
#pragma unroll
    for (int g = 0; g < 3; ++g) {
        const float* pa = W_hh + (size_t)(g * H + jA) * H;
        const float* pb = W_hh + (size_t)(g * H + jB) * H;
#pragma unroll
        for (int k = 0; k < 8; ++k) {
            wA[g][k] = *(const v2f*)&pa[2 * lane + 128 * k];
            wB[g][k] = *(const v2f*)&pb[2 * lane + 128 * k];
        }
    }
    const float brA = b_ih[jA] + b_hh[jA],         brB = b_ih[jB] + b_hh[jB];
    const float bzA = b_ih[H + jA] + b_hh[H + jA], bzB = b_ih[H + jB] + b_hh[H + jB];
    const float binA = b_ih[2 * H + jA],           binB = b_ih[2 * H + jB];
    const float bhnA = b_hh[2 * H + jA],           bhnB = b_hh[2 * H + jB];
    const float bjA = u0[jA] - c[jA],              bjB = u0[jB] - c[jB];

    int credits = 8;                 // per-thread fast-path health (tid<512 use it)

    // ---- epoch 0: publish Richardson iterate 0 (h = b) ----
    if (lane == 0) publish2_(fastb, slowb, 0, jA, bjA, bjB);

    // ---- solve epochs 1..48: h_r = b + h_{r-1} - A h_{r-1} ----
    const float* arA = Amat + (size_t)jA * H;
    const float* arB = Amat + (size_t)jB * H;
    for (int r = 1; r <= SOLVE_ITERS; ++r) {
        const int p = (r - 1) & 1;
        if (tid < 512)
            *(v2f*)&hlds[p][2 * tid] = consume2_(fastb, slowb, r - 1, 2 * tid, credits);
        __syncthreads();
        v2f aA = {0.f, 0.f}, aB = {0.f, 0.f};
#pragma unroll
        for (int k = 0; k < 8; ++k) {
            const v2f hv = *(const v2f*)&hlds[p][2 * lane + 128 * k];
            aA += (*(const v2f*)&arA[2 * lane + 128 * k]) * hv;
            aB += (*(const v2f*)&arB[2 * lane + 128 * k]) * hv;
        }
        float sA = aA.x + aA.y, sB = aB.x + aB.y;
#pragma unroll
        for (int m = 32; m >= 1; m >>= 1) {
            sA += __shfl_xor(sA, m, 64);
            sB += __shfl_xor(sB, m, 64);
        }
        if (lane == 0) {
            const float hA = bjA + hlds[p][jA] - sA;
            const float hB = bjB + hlds[p][jB] - sB;
            publish2_(fastb, slowb, r, jA, hA, hB);
            if (r == SOLVE_ITERS) {                  // hs row 0 = h0
                v2f o; o.x = hA; o.y = hB;
                *(v2f*)&out[jA] = o;
            }
        }
    }

    // ---- GRU epochs: step t consumes epoch 48+t-1, publishes 48+t ----
    for (int t = 1; t < T; ++t) {
        const int e = SOLVE_ITERS + t;
        const int p = (e - 1) & 1;
        if (tid < 512)
            *(v2f*)&hlds[p][2 * tid] = consume2_(fastb, slowb, e - 1, 2 * tid, credits);
        __syncthreads();

        v2f aR = {0.f, 0.f}, aZ = {0.f, 0.f}, aN = {0.f, 0.f};
        v2f bR = {0.f, 0.f}, bZ = {0.f, 0.f}, bN = {0.f, 0.f};
#pragma unroll
        for (int k = 0; k < 8; ++k) {
            const v2f hv = *(const v2f*)&hlds[p][2 * lane + 128 * k];
            aR += wA[0][k] * hv; aZ += wA[1][k] * hv; aN += wA[2][k] * hv;
            bR += wB[0][k] * hv; bZ += wB[1][k] * hv; bN += wB[2][k] * hv;
        }
        float sAr = aR.x + aR.y, sAz = aZ.x + aZ.y, sAn = aN.x + aN.y;
        float sBr = bR.x + bR.y, sBz = bZ.x + bZ.y, sBn = bN.x + bN.y;
#pragma unroll
        for (int m = 32; m >= 1; m >>= 1) {
            sAr += __shfl_xor(sAr, m, 64); sAz += __shfl_xor(sAz, m, 64);
            sAn += __shfl_xor(sAn, m, 64); sBr += __shfl_xor(sBr, m, 64);
            sBz += __shfl_xor(sBz, m, 64); sBn += __shfl_xor(sBn, m, 64);
        }
        if (lane == 0) {
            const float rA = sigmoidf_(brA + sAr);
            const float zA = sigmoidf_(bzA + sAz);
            const float nA = tanh_fast_(binA + rA * (sAn + bhnA));
            const float hA = (1.f - zA) * nA + zA * hlds[p][jA];
            const float rB = sigmoidf_(brB + sBr);
            const float zB = sigmoidf_(bzB + sBz);
            const float nB = tanh_fast_(binB + rB * (sBn + bhnB));
            const float hB = (1.f - zB) * nB + zB * hlds[p][jB];
            publish2_(fastb, slowb, e, jA, hA, hB);   // chain-critical first
            v2f o; o.x = hA; o.y = hB;
            *(v2f*)&out[(size_t)t * H + jA] = o;      // plain; read post-kernel
        }
    }
}

// In-place affine map out[t] <- A @ h[t] + c (R6/R7-proven tiled GEMM).
#define ORT 8
__global__ __launch_bounds__(256) void obs_kernel(
    const float* __restrict__ A,
    const float* __restrict__ c,
    float* __restrict__ out)
{
    __shared__ float hl[ORT][H];
    __shared__ float at[64][65];
    const int tid = threadIdx.x;
    const int t0  = blockIdx.x * ORT;
    for (int i = tid; i < ORT * H / 4; i += 256)
        ((float4*)&hl[0][0])[i] = ((const float4*)(out + (size_t)t0 * H))[i];
    __syncthreads();
    const int li = tid & 63, lt2 = (tid >> 6) * 2;
    for (int it = 0; it < 16; ++it) {
        const int i0 = it * 64;
        float acc0 = c[i0 + li], acc1 = acc0;
        for (int jt = 0; jt < 16; ++jt) {
            const int j0 = jt * 64;
            __syncthreads();
            {
                const int r0 = tid >> 4, cq = (tid & 15) * 4;
                for (int rr = r0; rr < 64; rr += 16) {
                    const float4 v = *(const float4*)&A[(size_t)(i0 + rr) * H + j0 + cq];
                    at[rr][cq] = v.x; at[rr][cq + 1] = v.y;
                    at[rr][cq + 2] = v.z; at[rr][cq + 3] = v.w;
                }
            }
            __syncthreads();
#pragma unroll 16
            for (int jx = 0; jx < 64; ++jx) {
                const float av = at[li][jx];
                acc0 += av * hl[lt2][j0 + jx];
                acc1 += av * hl[lt2 + 1][j0 + jx];
            }
        }
        out[(size_t)(t0 + lt2) * H + i0 + li]     = acc0;
        out[(size_t)(t0 + lt2 + 1) * H + i0 + li] = acc1;
    }
}

extern "C" void kernel_launch(void* const* d_in, const int* in_sizes, int n_in,
                              void* d_out, int out_size, void* d_ws, size_t ws_size,
                              hipStream_t stream) {
    // inputs: 0 ts, 1 u0, 2 W_ih (unused: control==0), 3 W_hh, 4 b_ih,
    //         5 b_hh, 6 A, 7 c
    const float* u0   = (const float*)d_in[1];
    const float* W_hh = (const float*)d_in[3];
    const float* b_ih = (const float*)d_in[4];
    const float* b_hh = (const float*)d_in[5];
    const float* A    = (const float*)d_in[6];
    const float* c    = (const float*)d_in[7];
    float* out  = (float*)d_out;
    u64* fastb = (u64*)d_ws;                         // 16 KB
    u64* slowb = (u64*)((char*)d_ws + 16384);        // 16 KB; salts reject poison

    hipLaunchKernelGGL(rnn_kernel, dim3(NLAUNCH), dim3(TPB), 0, stream,
                       u0, W_hh, b_ih, b_hh, A, c, out, fastb, slowb);
    hipLaunchKernelGGL(obs_kernel, dim3(T / ORT), dim3(256), 0, stream,
                       A, c, out);
}